// Round 5
// baseline (831.014 us; speedup 1.0000x reference)
//
#include <hip/hip_runtime.h>
#include <stdint.h>

// Problem constants
#define B_ROWS   10240
#define IN_DIM   4096
#define OUT_DIM  4096
#define K_CL     10
#define QMAXF    255.0f

typedef __attribute__((ext_vector_type(8)))  int   int8v;
typedef __attribute__((ext_vector_type(16))) float f32x16;

// ---------- helpers ----------
__device__ inline float devinf() { return __int_as_float(0x7f800000); }

__device__ inline void atomicMinF(float* addr, float v) {
    if (v >= 0.f) atomicMin((int*)addr, __float_as_int(v));
    else          atomicMax((unsigned int*)addr, __float_as_uint(v));
}
__device__ inline void atomicMaxF(float* addr, float v) {
    if (v >= 0.f) atomicMax((int*)addr, __float_as_int(v));
    else          atomicMin((unsigned int*)addr, __float_as_uint(v));
}

__device__ inline unsigned short f2bf(float f) {
    unsigned int u = __float_as_uint(f);
    u += 0x7fffu + ((u >> 16) & 1u);
    return (unsigned short)(u >> 16);
}
__device__ inline float bf2f(unsigned short u) {
    return __uint_as_float((unsigned)u << 16);
}

// pack 4 floats -> 4x fp8 e4m3 (OCP), RNE + saturate
__device__ inline unsigned f2fp8x4(float a, float b, float c, float d) {
    int v = 0;
    v = __builtin_amdgcn_cvt_pk_fp8_f32(a, b, v, false);
    v = __builtin_amdgcn_cvt_pk_fp8_f32(c, d, v, true);
    return (unsigned)v;
}

// ---------- ws layout ----------
// floats at base: [0]=wmin [1]=wmax [2..11]=cl min [12..21]=cl max [22..41]=s3,z3
// byte 256: x_f8 frag-major (10240*4096) ; w_f8 frag-major (4096*4096) ;
// then (if room) C_bf16 (10240*4096*2)
#define XBYTES  ((size_t)B_ROWS * IN_DIM)
#define WBYTES  ((size_t)OUT_DIM * IN_DIM)
#define CBBYTES ((size_t)B_ROWS * OUT_DIM * 2)

// Fragment-major layout for an R x 4096 fp8 matrix (NT gemm, 32x32x64 MFMA):
//   tile (rb,kb): rows rb*32..+32, k cols kb*64..+64  -> 2048 contiguous bytes
//   within tile: byte off = j16*1024 + lane*16, where lane = kh*32+m32,
//   holding M[rb*32+m32][kb*64 + kh*32 + j16*16 .. +16].
//   tile order: rb-major, kb inner  (tile base = (rb*64+kb)*2048).
// A wave's A-fragment load = 2 fully-coalesced dwordx4 (1 KB each).

__global__ void k_init(float* st) {
    int t = threadIdx.x;
    if (t == 0) { st[0] = devinf(); st[1] = -devinf(); }
    if (t >= 2 && t < 12)  st[t] = devinf();
    if (t >= 12 && t < 22) st[t] = -devinf();
}

__global__ void k_wminmax(const float4* __restrict__ w, int n4, float* st) {
    float mn = devinf(), mx = -devinf();
    for (int i = blockIdx.x * blockDim.x + threadIdx.x; i < n4;
         i += gridDim.x * blockDim.x) {
        float4 v = w[i];
        mn = fminf(mn, fminf(fminf(v.x, v.y), fminf(v.z, v.w)));
        mx = fmaxf(mx, fmaxf(fmaxf(v.x, v.y), fmaxf(v.z, v.w)));
    }
    for (int o = 32; o; o >>= 1) {
        mn = fminf(mn, __shfl_down(mn, o));
        mx = fmaxf(mx, __shfl_down(mx, o));
    }
    __shared__ float smn[4], smx[4];
    int lane = threadIdx.x & 63, wv = threadIdx.x >> 6;
    if (lane == 0) { smn[wv] = mn; smx[wv] = mx; }
    __syncthreads();
    if (threadIdx.x == 0) {
        for (int i = 1; i < 4; ++i) { mn = fminf(mn, smn[i]); mx = fmaxf(mx, smx[i]); }
        atomicMinF(&st[0], mn);
        atomicMaxF(&st[1], mx);
    }
}

// fused transform: W fake-quant -> fp8 frag-major; x -> fp8 frag-major.
// Output-indexed: each thread writes one 16B chunk (coalesced); reads 64B of a row.
__global__ void k_quantcast(const float4* __restrict__ w, uint4* __restrict__ wo,
                            int nw16,
                            const float4* __restrict__ x, uint4* __restrict__ xo,
                            int nx16, const float* st) {
    float mn = st[0], mx = st[1];
    float s = (mx - mn) / QMAXF;
    float z = -rintf(mn / s);
    int total = nw16 + nx16;
    for (int i = blockIdx.x * blockDim.x + threadIdx.x; i < total;
         i += gridDim.x * blockDim.x) {
        int T; const float4* src; uint4* dst; int doq;
        if (i < nw16) { T = i;        src = w; dst = wo; doq = 1; }
        else          { T = i - nw16; src = x; dst = xo; doq = 0; }
        int lane = T & 63, j16 = (T >> 6) & 1, kb = (T >> 7) & 63, rb = T >> 13;
        int row  = rb * 32 + (lane & 31);
        int colf = kb * 64 + (lane >> 5) * 32 + j16 * 16;
        size_t sb = ((size_t)row * 4096 + colf) >> 2;  // float4 index
        uint4 r; unsigned* rp = (unsigned*)&r;
#pragma unroll
        for (int j = 0; j < 4; ++j) {
            float4 v = src[sb + j];
            if (doq) {
                v.x = (fminf(fmaxf(rintf(v.x / s + z), 0.f), QMAXF) - z) * s;
                v.y = (fminf(fmaxf(rintf(v.y / s + z), 0.f), QMAXF) - z) * s;
                v.z = (fminf(fmaxf(rintf(v.z / s + z), 0.f), QMAXF) - z) * s;
                v.w = (fminf(fmaxf(rintf(v.w / s + z), 0.f), QMAXF) - z) * s;
            }
            rp[j] = f2fp8x4(v.x, v.y, v.z, v.w);
        }
        dst[T] = r;
    }
}

#define MK8(lo, hi) int8v{(int)(lo).x, (int)(lo).y, (int)(lo).z, (int)(lo).w, \
                          (int)(hi).x, (int)(hi).y, (int)(hi).z, (int)(hi).w}

// MX-fp8 NT GEMM, LDS-free: fragments loaded straight from frag-major global.
// Block tile 128x128, 4 waves 2x2, wave tile 64x64 = 2x2 of 32x32x64 (scales=1.0).
// No K-loop barriers -> no vmcnt(0) drain; 2-stage manual prefetch.
// Light resync every 16 kb-iters to keep wave pairs converged for L1 reuse.
// Epilogue: bias, per-cluster min/max atomics, C stored bf16 (ws) or fp32 (out).
__global__ __launch_bounds__(256) void k_gemm(
    const uint4* __restrict__ Af, const uint4* __restrict__ Bf,
    const float* __restrict__ bias, float* __restrict__ outC,
    unsigned short* __restrict__ cb, int use_bf16,
    float* clmin, float* clmax)
{
    __shared__ float red[8];
    int tid = threadIdx.x;
    int wv = tid >> 6, lane = tid & 63;
    int wr = wv >> 1, wc = wv & 1;           // wave 2x2 position
    int m32 = lane & 31, kh = lane >> 5;     // MFMA lane decomposition
    int bM = blockIdx.y, bN = blockIdx.x;

    // uint4-unit strides: tile = 128, kb step = 128, rb step = 64*128 = 8192
    const uint4* pa = Af + (size_t)(bM * 4 + wr * 2) * 8192 + lane;
    const uint4* pb = Bf + (size_t)(bN * 4 + wc * 2) * 8192 + lane;

    f32x16 acc[2][2] = {};
    uint4 a[2][2], b[2][2], an[2][2], bn[2][2];

#define LDF(kb, A_, B_) do { int _o = (kb) * 128;                          \
    A_[0][0] = pa[_o];        A_[0][1] = pa[_o + 64];                      \
    A_[1][0] = pa[_o + 8192]; A_[1][1] = pa[_o + 8192 + 64];               \
    B_[0][0] = pb[_o];        B_[0][1] = pb[_o + 64];                      \
    B_[1][0] = pb[_o + 8192]; B_[1][1] = pb[_o + 8192 + 64]; } while (0)

#define MM(A_, B_) do {                                                     \
    int8v _a0 = MK8(A_[0][0], A_[0][1]), _a1 = MK8(A_[1][0], A_[1][1]);     \
    int8v _b0 = MK8(B_[0][0], B_[0][1]), _b1 = MK8(B_[1][0], B_[1][1]);     \
    acc[0][0] = __builtin_amdgcn_mfma_scale_f32_32x32x64_f8f6f4(            \
        _a0, _b0, acc[0][0], 0, 0, 0, 0x7f, 0, 0x7f);                       \
    acc[0][1] = __builtin_amdgcn_mfma_scale_f32_32x32x64_f8f6f4(            \
        _a0, _b1, acc[0][1], 0, 0, 0, 0x7f, 0, 0x7f);                       \
    acc[1][0] = __builtin_amdgcn_mfma_scale_f32_32x32x64_f8f6f4(            \
        _a1, _b0, acc[1][0], 0, 0, 0, 0x7f, 0, 0x7f);                       \
    acc[1][1] = __builtin_amdgcn_mfma_scale_f32_32x32x64_f8f6f4(            \
        _a1, _b1, acc[1][1], 0, 0, 0, 0x7f, 0, 0x7f); } while (0)

    LDF(0, a, b);
    for (int kb = 0; kb < 64; kb += 2) {
        if ((kb & 15) == 0) __syncthreads();   // bound wave drift (L1 reuse)
        LDF(kb + 1, an, bn);
        MM(a, b);
        int kn = (kb + 2 < 64) ? kb + 2 : 63;  // tail: harmless reload (L1 hit)
        LDF(kn, a, b);
        MM(an, bn);
    }
#undef LDF
#undef MM

    // epilogue
    float bv[2];
#pragma unroll
    for (int ni = 0; ni < 2; ++ni)
        bv[ni] = bias[bN * 128 + wc * 64 + ni * 32 + m32];

    float mn = devinf(), mx = -devinf();
#pragma unroll
    for (int mi = 0; mi < 2; ++mi) {
        int rbase = bM * 128 + wr * 64 + mi * 32 + 4 * kh;
#pragma unroll
        for (int ni = 0; ni < 2; ++ni) {
            int c = bN * 128 + wc * 64 + ni * 32 + m32;
#pragma unroll
            for (int reg = 0; reg < 16; ++reg) {
                int row = rbase + (reg & 3) + 8 * (reg >> 2);  // 32x32 C/D mapping
                float v = acc[mi][ni][reg] + bv[ni];
                if (use_bf16) cb[(size_t)row * OUT_DIM + c] = f2bf(v);
                else          outC[(size_t)row * OUT_DIM + c] = v;
                mn = fminf(mn, v);
                mx = fmaxf(mx, v);
            }
        }
    }
    for (int o = 32; o; o >>= 1) {
        mn = fminf(mn, __shfl_down(mn, o));
        mx = fmaxf(mx, __shfl_down(mx, o));
    }
    if (lane == 0) { red[wv] = mn; red[4 + wv] = mx; }
    __syncthreads();
    if (tid == 0) {
        for (int i = 1; i < 4; ++i) { mn = fminf(mn, red[i]); mx = fmaxf(mx, red[4 + i]); }
        int cl = bM >> 3;  // 8 row-blocks of 128 per 1024-row cluster
        atomicMinF(&clmin[cl], mn);
        atomicMaxF(&clmax[cl], mx);
    }
}

// EMA range update + qparams; writes new_range to out tail
__global__ void k_range(const float* st, const float* __restrict__ act_range,
                        const int* __restrict__ ci, float* out_tail, float* qp) {
    int t = threadIdx.x;
    if (t < K_CL) {
        out_tail[2 * t]     = act_range[2 * t];
        out_tail[2 * t + 1] = act_range[2 * t + 1];
    }
    __syncthreads();
    if (t < K_CL) {
        int c = ci[2 * t];
        float omn = act_range[2 * c], omx = act_range[2 * c + 1];
        float nm = omn * 0.999f + st[2 + t] * 0.001f;
        float nx = omx * 0.999f + st[12 + t] * 0.001f;
        out_tail[2 * c]     = nm;
        out_tail[2 * c + 1] = nx;
        float s = (nx - nm) / QMAXF;
        float z = -rintf(nm / s);
        qp[t] = s;
        qp[K_CL + t] = z;
    }
}

__device__ inline float fq(float v, float s, float z) {
    return (fminf(fmaxf(rintf(v / s + z), 0.f), QMAXF) - z) * s;
}

// per-cluster fake-quantize: bf16 C (ws) -> fp32 out. 8 elems/thread/iter.
__global__ void k_qout_bf(const uint4* __restrict__ cb, float4* __restrict__ out,
                          const float* __restrict__ qp, int n8) {
    for (int i = blockIdx.x * blockDim.x + threadIdx.x; i < n8;
         i += gridDim.x * blockDim.x) {
        int cl = i >> 19;  // 2^22 elems per cluster / 8 = 2^19 groups
        float s = qp[cl], z = qp[K_CL + cl];
        uint4 u = cb[i];
        float4 a, b;
        a.x = fq(bf2f((unsigned short)(u.x & 0xffff)), s, z);
        a.y = fq(bf2f((unsigned short)(u.x >> 16)),    s, z);
        a.z = fq(bf2f((unsigned short)(u.y & 0xffff)), s, z);
        a.w = fq(bf2f((unsigned short)(u.y >> 16)),    s, z);
        b.x = fq(bf2f((unsigned short)(u.z & 0xffff)), s, z);
        b.y = fq(bf2f((unsigned short)(u.z >> 16)),    s, z);
        b.z = fq(bf2f((unsigned short)(u.w & 0xffff)), s, z);
        b.w = fq(bf2f((unsigned short)(u.w >> 16)),    s, z);
        out[2 * i]     = a;
        out[2 * i + 1] = b;
    }
}

// fallback: in-place fp32 fake-quantize
__global__ void k_qout_f32(float4* __restrict__ out, const float* __restrict__ qp,
                           int n4) {
    for (int i = blockIdx.x * blockDim.x + threadIdx.x; i < n4;
         i += gridDim.x * blockDim.x) {
        int cl = i >> 20;
        float s = qp[cl], z = qp[K_CL + cl];
        float4 v = out[i];
        v.x = fq(v.x, s, z); v.y = fq(v.y, s, z);
        v.z = fq(v.z, s, z); v.w = fq(v.w, s, z);
        out[i] = v;
    }
}

extern "C" void kernel_launch(void* const* d_in, const int* in_sizes, int n_in,
                              void* d_out, int out_size, void* d_ws, size_t ws_size,
                              hipStream_t stream) {
    const float* x         = (const float*)d_in[0];
    const float* w         = (const float*)d_in[1];
    const float* bias      = (const float*)d_in[2];
    const float* act_range = (const float*)d_in[3];
    const int*   ci        = (const int*)d_in[4];
    float* out = (float*)d_out;

    float* st = (float*)d_ws;
    unsigned char* x_f8 = (unsigned char*)d_ws + 256;
    unsigned char* w_f8 = x_f8 + XBYTES;
    unsigned short* cb  = (unsigned short*)(w_f8 + WBYTES);

    const int use_bf16 = (ws_size >= 256 + XBYTES + WBYTES + CBBYTES) ? 1 : 0;

    k_init<<<1, 64, 0, stream>>>(st);
    k_wminmax<<<2048, 256, 0, stream>>>((const float4*)w, OUT_DIM * IN_DIM / 4, st);
    k_quantcast<<<4096, 256, 0, stream>>>(
        (const float4*)w, (uint4*)w_f8, OUT_DIM * IN_DIM / 16,
        (const float4*)x, (uint4*)x_f8, B_ROWS * IN_DIM / 16, st);
    dim3 grid(OUT_DIM / 128, B_ROWS / 128);
    k_gemm<<<grid, 256, 0, stream>>>((const uint4*)x_f8, (const uint4*)w_f8,
                                     bias, out, cb, use_bf16, st + 2, st + 12);
    k_range<<<1, 64, 0, stream>>>(st, act_range, ci,
                                  out + (size_t)B_ROWS * OUT_DIM, st + 22);
    if (use_bf16)
        k_qout_bf<<<4096, 256, 0, stream>>>((const uint4*)cb, (float4*)out,
                                            st + 22, B_ROWS * OUT_DIM / 8);
    else
        k_qout_f32<<<4096, 256, 0, stream>>>((float4*)out, st + 22,
                                             B_ROWS * OUT_DIM / 4);
}